// Round 14
// baseline (817.985 us; speedup 1.0000x reference)
//
#include <hip/hip_runtime.h>
#include <math.h>

constexpr int Bn = 8;
constexpr int Np = 2048;
constexpr int Kn = 32;
constexpr float NEGS = 0.2f;

typedef __attribute__((ext_vector_type(8))) short short8;
typedef __attribute__((ext_vector_type(4))) float f32x4;
typedef unsigned short ushortT;

__device__ __forceinline__ float lrelu(float v) { return v > 0.f ? v : NEGS * v; }

// DPP-based max step; ctrl/rmask as template args (builtin requires ICE operands)
template<int CTRL, int RMASK>
__device__ __forceinline__ float dppmax(float v) {
    int o = __float_as_int(v);
    int s = __builtin_amdgcn_update_dpp(o, o, CTRL, RMASK, 0xf, false);
    return fmaxf(v, __int_as_float(s));
}
// full 64-lane max via DPP (valid in lane 63), then readlane-broadcast
__device__ __forceinline__ float wave_max_dpp(float v) {
    v = dppmax<0x111, 0xf>(v);   // row_shr:1
    v = dppmax<0x112, 0xf>(v);   // row_shr:2
    v = dppmax<0x114, 0xf>(v);   // row_shr:4
    v = dppmax<0x118, 0xf>(v);   // row_shr:8
    v = dppmax<0x142, 0xa>(v);   // row_bcast:15 -> rows 1,3
    v = dppmax<0x143, 0xc>(v);   // row_bcast:31 -> row 3 (and 2)
    return __int_as_float(__builtin_amdgcn_readlane(__float_as_int(v), 63));
}

// split fp32 -> bf16 hi (truncate) + bf16 lo (residual, truncate); packed 2-at-a-time
__device__ __forceinline__ void cvt2u(float a, float b, unsigned& h, unsigned& l) {
    unsigned ua = __float_as_uint(a), ub = __float_as_uint(b);
    h = (ua >> 16) | (ub & 0xffff0000u);
    float ra = a - __uint_as_float(ua & 0xffff0000u);
    float rb = b - __uint_as_float(ub & 0xffff0000u);
    l = (__float_as_uint(ra) >> 16) | (__float_as_uint(rb) & 0xffff0000u);
}

// x [B,3,N] -> pts point-major [B*N, 4] (pad lane = 0)
__global__ __launch_bounds__(256) void k_transpose(const float* __restrict__ x, float* __restrict__ pts) {
    int i = blockIdx.x * 256 + threadIdx.x;
    int b = i / Np, n = i % Np;
    float p0 = x[((size_t)b * 3 + 0) * Np + n];
    float p1 = x[((size_t)b * 3 + 1) * Np + n];
    float p2 = x[((size_t)b * 3 + 2) * Np + n];
    float4 v = make_float4(p0, p1, p2, 0.f);
    *(float4*)&pts[(size_t)i * 4] = v;
}

// xx[i] = sum_c pm[i*ld+c]^2 ; one wave per point, 4 points per block
__global__ __launch_bounds__(256) void k_xx(const float* __restrict__ pm, float* __restrict__ xxg, int C, int ld) {
    int wid = threadIdx.x >> 6, lane = threadIdx.x & 63;
    int pt = blockIdx.x * 4 + wid;
    const float* row = pm + (size_t)pt * ld;
    float acc = 0.f;
    for (int c = lane; c < C; c += 64) { float v = row[c]; acc = fmaf(v, v, acc); }
    #pragma unroll
    for (int off = 32; off; off >>= 1) acc += __shfl_down(acc, off, 64);
    if (lane == 0) xxg[pt] = acc;
}

// Pack points into mfma_16x16x32 B-fragment order (bf16 hi/lo), per batch.
// v2: 8-wide vectorized — one thread per (b,ks,nt,lane) handles j=0..7.
template<int C, int CK, int LD>
__global__ __launch_bounds__(256) void k_bpack(const float* __restrict__ Xpm,
                                               ushortT* __restrict__ Bh, ushortT* __restrict__ Bl) {
    constexpr int KS = CK / 32;
    int tid = blockIdx.x * 256 + threadIdx.x;   // Bn*KS*128*64 total
    int lane = tid & 63;
    int nt = (tid >> 6) & 127;
    int rest = tid >> 13;
    int ks = rest % KS;
    int b = rest / KS;
    int quad = lane >> 4;
    int n = nt * 16 + (lane & 15);
    int k0 = ks * 32 + quad * 8;
    size_t src = ((size_t)b * Np + n) * LD;
    unsigned h[4], l[4];
    if constexpr (LD >= 8) {
        const float4* p4 = (const float4*)(Xpm + src + k0);
        float4 va = p4[0], vb = p4[1];
        cvt2u(va.x, va.y, h[0], l[0]);
        cvt2u(va.z, va.w, h[1], l[1]);
        cvt2u(vb.x, vb.y, h[2], l[2]);
        cvt2u(vb.z, vb.w, h[3], l[3]);
    } else {
        float vv[8];
        #pragma unroll
        for (int j = 0; j < 8; ++j) {
            int k = k0 + j;
            vv[j] = (k < C) ? Xpm[src + k] : 0.f;
        }
        cvt2u(vv[0], vv[1], h[0], l[0]);
        cvt2u(vv[2], vv[3], h[1], l[1]);
        cvt2u(vv[4], vv[5], h[2], l[2]);
        cvt2u(vv[6], vv[7], h[3], l[3]);
    }
    size_t oi = (size_t)tid * 8;
    *(uint4*)&Bh[oi] = make_uint4(h[0], h[1], h[2], h[3]);
    *(uint4*)&Bl[oi] = make_uint4(l[0], l[1], l[2], l[3]);
}

// Distance compute for one column QUARTER (CC in 0..3, 512 columns each):
// wave w computes tiles ntl = w*2, w*2+1 (ng = CC*32 + ntl) -> dl in LDS.
template<int CC, int KS, int CPv, int SDv>
__device__ __forceinline__ void dist_compute(
    const ushortT* __restrict__ Ah, const ushortT* __restrict__ Al,
    float* __restrict__ dl, const float* __restrict__ xxg,
    const ushortT* __restrict__ Bh, const ushortT* __restrict__ Bl,
    int b, int w, int lane, int quad, int col,
    const float (&xmr)[4])
{
    short8 ah[KS], al[KS];
    #pragma unroll
    for (int ks = 0; ks < KS; ++ks) {
        ah[ks] = *(const short8*)&Ah[col * CPv + ks * 32 + quad * 8];
        al[ks] = *(const short8*)&Al[col * CPv + ks * 32 + quad * 8];
    }
    int ntl0 = w * 2, ntl1 = ntl0 + 1;
    int ng0 = CC * 32 + ntl0, ng1 = CC * 32 + ntl1;
    f32x4 a0 = (f32x4){0.f, 0.f, 0.f, 0.f};
    f32x4 a1 = (f32x4){0.f, 0.f, 0.f, 0.f};
    #pragma unroll
    for (int ks = 0; ks < KS; ++ks) {
        int bi0 = (((b * KS + ks) * 128 + ng0) * 64 + lane) * 8;
        int bi1 = (((b * KS + ks) * 128 + ng1) * 64 + lane) * 8;
        short8 bh0 = *(const short8*)(Bh + bi0);
        short8 bl0 = *(const short8*)(Bl + bi0);
        short8 bh1 = *(const short8*)(Bh + bi1);
        short8 bl1 = *(const short8*)(Bl + bi1);
        a0 = __builtin_amdgcn_mfma_f32_16x16x32_bf16(ah[ks], bh0, a0, 0, 0, 0);
        a1 = __builtin_amdgcn_mfma_f32_16x16x32_bf16(ah[ks], bh1, a1, 0, 0, 0);
        a0 = __builtin_amdgcn_mfma_f32_16x16x32_bf16(ah[ks], bl0, a0, 0, 0, 0);
        a1 = __builtin_amdgcn_mfma_f32_16x16x32_bf16(ah[ks], bl1, a1, 0, 0, 0);
        a0 = __builtin_amdgcn_mfma_f32_16x16x32_bf16(al[ks], bh0, a0, 0, 0, 0);
        a1 = __builtin_amdgcn_mfma_f32_16x16x32_bf16(al[ks], bh1, a1, 0, 0, 0);
    }
    float xn0 = xxg[b * Np + ng0 * 16 + col];
    float xn1 = xxg[b * Np + ng1 * 16 + col];
    #pragma unroll
    for (int r = 0; r < 4; ++r) {
        int m = quad * 4 + r;
        dl[m * SDv + ntl0 * 16 + col] = 2.f * a0[r] - xmr[r] - xn0;
        dl[m * SDv + ntl1 * 16 + col] = 2.f * a1[r] - xmr[r] - xn1;
    }
}

// MFMA kNN v12 (r12, kept): 4-pass column split, dl=[16][514].
template<int C, int CK, int LD>
__global__ __launch_bounds__(1024) void k_knn5(const float* __restrict__ Xpm,
                                               const ushortT* __restrict__ Bh, const ushortT* __restrict__ Bl,
                                               const float* __restrict__ xxg, int* __restrict__ idxo) {
    constexpr int KS = CK / 32, CP = CK + 8, CK4 = CK / 4, C4src = LD / 4;
    constexpr int SD = 514;
    extern __shared__ char smem[];
    ushortT* Ah = (ushortT*)smem;              // [16][CP]
    ushortT* Al = Ah + 16 * CP;                // [16][CP]
    float* xxm = (float*)(Al + 16 * CP);       // [16]
    float* dl = xxm + 16;                      // [16][SD] distances (one column-quarter)
    int nwg = gridDim.x;
    int cpx = nwg >> 3;                        // 128 when nwg=1024
    int logical = (blockIdx.x & 7) * cpx + (blockIdx.x >> 3);
    int b = logical / (Np / 16);
    int n0 = (logical % (Np / 16)) * 16;
    int t = threadIdx.x;
    const float4* Xp4 = (const float4*)Xpm;
    for (int e = t; e < 16 * CK4; e += 1024) {
        int r = e / CK4, c4 = e % CK4;
        float4 v = (c4 < C4src) ? Xp4[((size_t)b * Np + n0 + r) * C4src + c4] : make_float4(0.f, 0.f, 0.f, 0.f);
        unsigned h0, l0, h1, l1;
        cvt2u(v.x, v.y, h0, l0);
        cvt2u(v.z, v.w, h1, l1);
        *(uint2*)&Ah[r * CP + 4 * c4] = make_uint2(h0, h1);
        *(uint2*)&Al[r * CP + 4 * c4] = make_uint2(l0, l1);
    }
    if (t < 16) xxm[t] = xxg[b * Np + t + n0];
    __syncthreads();

    int w = t >> 6, lane = t & 63;
    int quad = lane >> 4, col = lane & 15;
    float xmr[4];
    #pragma unroll
    for (int r = 0; r < 4; ++r) xmr[r] = xxm[quad * 4 + r];

    const float* drow = dl + w * SD;
    float v0, v1, v2, v3, v4, v5, v6, v7, v8, v9, v10, v11, v12, v13, v14, v15;
    float v16, v17, v18, v19, v20, v21, v22, v23, v24, v25, v26, v27, v28, v29, v30, v31;

    dist_compute<0, KS, CP, SD>(Ah, Al, dl, xxg, Bh, Bl, b, w, lane, quad, col, xmr);
    __syncthreads();
    v0 = drow[lane + 0 * 64]; v1 = drow[lane + 1 * 64];
    v2 = drow[lane + 2 * 64]; v3 = drow[lane + 3 * 64];
    v4 = drow[lane + 4 * 64]; v5 = drow[lane + 5 * 64];
    v6 = drow[lane + 6 * 64]; v7 = drow[lane + 7 * 64];
    __syncthreads();
    dist_compute<1, KS, CP, SD>(Ah, Al, dl, xxg, Bh, Bl, b, w, lane, quad, col, xmr);
    __syncthreads();
    v8  = drow[lane + 0 * 64]; v9  = drow[lane + 1 * 64];
    v10 = drow[lane + 2 * 64]; v11 = drow[lane + 3 * 64];
    v12 = drow[lane + 4 * 64]; v13 = drow[lane + 5 * 64];
    v14 = drow[lane + 6 * 64]; v15 = drow[lane + 7 * 64];
    __syncthreads();
    dist_compute<2, KS, CP, SD>(Ah, Al, dl, xxg, Bh, Bl, b, w, lane, quad, col, xmr);
    __syncthreads();
    v16 = drow[lane + 0 * 64]; v17 = drow[lane + 1 * 64];
    v18 = drow[lane + 2 * 64]; v19 = drow[lane + 3 * 64];
    v20 = drow[lane + 4 * 64]; v21 = drow[lane + 5 * 64];
    v22 = drow[lane + 6 * 64]; v23 = drow[lane + 7 * 64];
    __syncthreads();
    dist_compute<3, KS, CP, SD>(Ah, Al, dl, xxg, Bh, Bl, b, w, lane, quad, col, xmr);
    __syncthreads();
    v24 = drow[lane + 0 * 64]; v25 = drow[lane + 1 * 64];
    v26 = drow[lane + 2 * 64]; v27 = drow[lane + 3 * 64];
    v28 = drow[lane + 4 * 64]; v29 = drow[lane + 5 * 64];
    v30 = drow[lane + 6 * 64]; v31 = drow[lane + 7 * 64];

    // ---- selection: per-lane sorted top-4 (val,idx) list ----
    float s0v = -INFINITY, s1v = -INFINITY, s2v = -INFINITY, s3v = -INFINITY;
    int s0i = 0, s1i = 0, s2i = 0, s3i = 0;

#define INS4(VV, JJ) { \
    bool b0 = (VV) > s0v, b1 = (VV) > s1v, b2 = (VV) > s2v, b3 = (VV) > s3v; \
    s3v = b2 ? s2v : (b3 ? (VV) : s3v);  s3i = b2 ? s2i : (b3 ? (JJ) : s3i); \
    s2v = b1 ? s1v : (b2 ? (VV) : s2v);  s2i = b1 ? s1i : (b2 ? (JJ) : s2i); \
    s1v = b0 ? s0v : (b1 ? (VV) : s1v);  s1i = b0 ? s0i : (b1 ? (JJ) : s1i); \
    s0v = b0 ? (VV) : s0v;               s0i = b0 ? (JJ) : s0i; \
}
    INS4(v0, 0)   INS4(v1, 1)   INS4(v2, 2)   INS4(v3, 3)
    INS4(v4, 4)   INS4(v5, 5)   INS4(v6, 6)   INS4(v7, 7)
    INS4(v8, 8)   INS4(v9, 9)   INS4(v10, 10) INS4(v11, 11)
    INS4(v12, 12) INS4(v13, 13) INS4(v14, 14) INS4(v15, 15)
    INS4(v16, 16) INS4(v17, 17) INS4(v18, 18) INS4(v19, 19)
    INS4(v20, 20) INS4(v21, 21) INS4(v22, 22) INS4(v23, 23)
    INS4(v24, 24) INS4(v25, 25) INS4(v26, 26) INS4(v27, 27)
    INS4(v28, 28) INS4(v29, 29) INS4(v30, 30) INS4(v31, 31)

    unsigned umask = 0u;
    int pops = 0;
    size_t ob = ((size_t)b * Np + n0 + w) * Kn;
    for (int it = 0; it < Kn; ++it) {
        float Wv = wave_max_dpp(s0v);
        unsigned long long mk = __ballot(s0v == Wv);
        int owner = __ffsll(mk) - 1;
        bool pred = (lane == owner);
        if (pred) idxo[ob + it] = lane + (s0i << 6);
        umask |= pred ? (1u << s0i) : 0u;
        pops = pred ? (pops + 1) : pops;
        s0v = pred ? s1v : s0v;  s0i = pred ? s1i : s0i;
        s1v = pred ? s2v : s1v;  s1i = pred ? s2i : s1i;
        s2v = pred ? s3v : s2v;  s2i = pred ? s3i : s2i;
        s3v = pred ? -INFINITY : s3v;
        bool need = pred && (pops >= 4);
        if (__ballot(need)) {          // wave-uniform scalar branch, ~never taken
            if (need) {
                pops = 0;
                s0v = s1v = s2v = s3v = -INFINITY;
                s0i = s1i = s2i = s3i = 0;
#define RINS(VV, JJ) { float vv_ = ((umask >> (JJ)) & 1u) ? -INFINITY : (VV); INS4(vv_, JJ) }
                RINS(v0, 0)   RINS(v1, 1)   RINS(v2, 2)   RINS(v3, 3)
                RINS(v4, 4)   RINS(v5, 5)   RINS(v6, 6)   RINS(v7, 7)
                RINS(v8, 8)   RINS(v9, 9)   RINS(v10, 10) RINS(v11, 11)
                RINS(v12, 12) RINS(v13, 13) RINS(v14, 14) RINS(v15, 15)
                RINS(v16, 16) RINS(v17, 17) RINS(v18, 18) RINS(v19, 19)
                RINS(v20, 20) RINS(v21, 21) RINS(v22, 22) RINS(v23, 23)
                RINS(v24, 24) RINS(v25, 25) RINS(v26, 26) RINS(v27, 27)
                RINS(v28, 28) RINS(v29, 29) RINS(v30, 30) RINS(v31, 31)
#undef RINS
            }
        }
    }
#undef INS4
}

// W split+scale+transpose (fp32, for k_ctr): WdsT[c][o] = (W[o][C+c]-W[o][c])*s[o]
__global__ __launch_bounds__(256) void k_wsplit(const float* __restrict__ W, const float* __restrict__ s,
                                                int C, int O, float* __restrict__ WnsT, float* __restrict__ WdsT) {
    int i = blockIdx.x * 256 + threadIdx.x;
    if (i >= C * O) return;
    int c = i / O, o = i % O;
    float a = W[(size_t)o * 2 * C + c];
    float q = W[(size_t)o * 2 * C + C + c];
    float sv = s[o];
    WnsT[i] = a * sv;
    WdsT[i] = (q - a) * sv;
}

// Pack neighbor-half of W (scaled) into mfma_16x16x32 B-fragment order, split bf16 hi/lo.
// v2: 8-wide vectorized.
__global__ __launch_bounds__(256) void k_wpack(const float* __restrict__ W, const float* __restrict__ s,
                                               int C, int O, ushortT* __restrict__ Bh, ushortT* __restrict__ Bl) {
    int tid = blockIdx.x * 256 + threadIdx.x;   // C*O/8 total
    if (tid >= (C * O) / 8) return;
    int lane = tid & 63;
    int nt = tid >> 6;                          // ks*NT + nt combined
    int NT = O / 16;
    int ks = nt / NT;
    nt = nt % NT;
    int quad = lane >> 4;
    int o = nt * 16 + (lane & 15);
    int k0 = ks * 32 + quad * 8;
    const float* wr = W + (size_t)o * 2 * C + k0;
    float4 va = *(const float4*)wr;
    float4 vb = *(const float4*)(wr + 4);
    float sv = s[o];
    unsigned h[4], l[4];
    cvt2u(va.x * sv, va.y * sv, h[0], l[0]);
    cvt2u(va.z * sv, va.w * sv, h[1], l[1]);
    cvt2u(vb.x * sv, vb.y * sv, h[2], l[2]);
    cvt2u(vb.z * sv, vb.w * sv, h[3], l[3]);
    size_t oi = (size_t)tid * 8;
    *(uint4*)&Bh[oi] = make_uint4(h[0], h[1], h[2], h[3]);
    *(uint4*)&Bl[oi] = make_uint4(l[0], l[1], l[2], l[3]);
}

// Pack W5 (scaled by s5) [1024][512] into fragment order: KS=16, NT=64.
// v2: 8-wide vectorized.
__global__ __launch_bounds__(256) void k_w5pack(const float* __restrict__ W5, const float* __restrict__ s5,
                                                ushortT* __restrict__ Bh, ushortT* __restrict__ Bl) {
    int tid = blockIdx.x * 256 + threadIdx.x;   // 64K total
    int lane = tid & 63;
    int nt = (tid >> 6) & 63;
    int ks = tid >> 12;
    int quad = lane >> 4;
    int o = nt * 16 + (lane & 15);
    int k0 = ks * 32 + quad * 8;
    const float* wr = W5 + (size_t)o * 512 + k0;
    float4 va = *(const float4*)wr;
    float4 vb = *(const float4*)(wr + 4);
    float sv = s5[o];
    unsigned h[4], l[4];
    cvt2u(va.x * sv, va.y * sv, h[0], l[0]);
    cvt2u(va.z * sv, va.w * sv, h[1], l[1]);
    cvt2u(vb.x * sv, vb.y * sv, h[2], l[2]);
    cvt2u(vb.z * sv, vb.w * sv, h[3], l[3]);
    size_t oi = (size_t)tid * 8;
    *(uint4*)&Bh[oi] = make_uint4(h[0], h[1], h[2], h[3]);
    *(uint4*)&Bl[oi] = make_uint4(l[0], l[1], l[2], l[3]);
}

// cb[n][o] = sum_c ctr[n][c]*WdsT[c][o] + b[o].  32 points per block.
template<int C, int O, int OPT>
__global__ __launch_bounds__(256) void k_ctr(const float* __restrict__ Xpm, const float* __restrict__ WdsT,
                                             const float* __restrict__ bg, float* __restrict__ cb) {
    constexpr int OG = O / OPT, MG = 256 / OG, MPT = 32 / MG;
    constexpr int C4 = C / 4;
    __shared__ float xs[32][C];
    int b = blockIdx.x / (Np / 32);
    int n0 = (blockIdx.x % (Np / 32)) * 32;
    int t = threadIdx.x;
    const float4* Xp4 = (const float4*)Xpm;
    for (int e = t; e < 32 * C4; e += 256) {
        int pt = e / C4, c4 = e % C4;
        *(float4*)&xs[pt][4 * c4] = Xp4[((size_t)b * Np + n0 + pt) * C4 + c4];
    }
    __syncthreads();
    int og = t % OG, mg = t / OG;
    int o0 = og * OPT;
    float acc[MPT][OPT] = {};
    for (int c = 0; c < C; ++c) {
        float wv[OPT];
        #pragma unroll
        for (int p4 = 0; p4 < OPT / 4; ++p4)
            *(float4*)&wv[4 * p4] = *(const float4*)&WdsT[(size_t)c * O + o0 + 4 * p4];
        #pragma unroll
        for (int m = 0; m < MPT; ++m) {
            float xv = xs[mg * MPT + m][c];
            #pragma unroll
            for (int p = 0; p < OPT; ++p) acc[m][p] = fmaf(wv[p], xv, acc[m][p]);
        }
    }
    #pragma unroll
    for (int m = 0; m < MPT; ++m) {
        #pragma unroll
        for (int p = 0; p < OPT; ++p) {
            int o = o0 + p;
            cb[((size_t)b * Np + n0 + mg * MPT + m) * O + o] = acc[m][p] + bg[o];
        }
    }
}

// MFMA EdgeConv GEMM v8 = r13 v7 + bijective XCD swizzle on the grid.
// Theory: grid=8192 blocks round-robined over 8 XCDs made every XCD's 4MB
// L2 cache all 8 batches' X panels (8-16MB) -> thrash; FETCH 41.5MB vs
// ~18MB ideal. Swizzle gives each XCD one contiguous batch (1024 blocks =
// exactly Np/PTS), whose X (1-2MB) + cb panel fit its private L2 -> random
// A-gathers become L2 hits (~200cy vs ~900cy). Mechanism validated on knn
// in r2 (FETCH 37->8.3MB). DO NOT raise min-waves (spill, r7/r9).
template<int C, int O, int PTS>
__global__ __launch_bounds__(256, 4) void k_ec3(const float* __restrict__ Xpm, const int* __restrict__ idxg,
                                                const ushortT* __restrict__ Bh, const ushortT* __restrict__ Bl,
                                                const float* __restrict__ cb,
                                                float* __restrict__ Ypm) {
    static_assert(PTS == 2, "M=64 mapping");
    constexpr int M = 64, NT = O / 16, NT4 = NT / 4, KS = C / 32, C4 = C / 4;
    constexpr int IH = (NT4 > 2) ? 2 : 1, IW = NT4 / IH;
    static_assert(NT4 >= 1, "O>=64");
    // A in fragment-linear order: [(mt*KS+ks)*64 + lane] * 8 shorts
    __shared__ ushortT AhF[M * C];
    __shared__ ushortT AlF[M * C];
    int nwg = gridDim.x;                        // 8192 (== Bn * Np/PTS), % 8 == 0
    int cpx = nwg >> 3;
    int logical = (blockIdx.x & 7) * cpx + (blockIdx.x >> 3);
    int b = logical / (Np / PTS);
    int n0 = (logical % (Np / PTS)) * PTS;
    int t = threadIdx.x;
    int w = t >> 6, lane = t & 63;
    int quad = lane >> 4, col = lane & 15;
    const int* ip = idxg + ((size_t)b * Np + n0) * Kn;
    const float4* Xp4 = (const float4*)Xpm;

    // early B prefetch (ih=0, ks=0) — in flight during A staging
    size_t b00 = (((size_t)(w * NT4)) * 64 + lane) * 8;
    short8 pbh = *(const short8*)(Bh + b00);
    short8 pbl = *(const short8*)(Bl + b00);

    // T14 staging: issue ALL global A-gather loads, then cvt+LDS-write.
    int grow = ip[w * 16 + col];
    size_t gbase = ((size_t)b * Np + grow) * C4;
    float4 va[KS], vb[KS];
    #pragma unroll
    for (int ks = 0; ks < KS; ++ks) {
        int c4a = (ks * 32 + quad * 8) >> 2;
        va[ks] = Xp4[gbase + c4a];
        vb[ks] = Xp4[gbase + c4a + 1];
    }
    #pragma unroll
    for (int ks = 0; ks < KS; ++ks) {
        unsigned h0, l0, h1, l1, h2, l2, h3, l3;
        cvt2u(va[ks].x, va[ks].y, h0, l0);
        cvt2u(va[ks].z, va[ks].w, h1, l1);
        cvt2u(vb[ks].x, vb[ks].y, h2, l2);
        cvt2u(vb[ks].z, vb[ks].w, h3, l3);
        int fo = ((w * KS + ks) * 64 + lane) * 8;
        *(uint4*)&AhF[fo] = make_uint4(h0, h1, h2, h3);
        *(uint4*)&AlF[fo] = make_uint4(l0, l1, l2, l3);
    }
    __syncthreads();

    #pragma unroll
    for (int ih = 0; ih < IH; ++ih) {
        f32x4 acc[4][IW];
        #pragma unroll
        for (int mt = 0; mt < 4; ++mt)
            #pragma unroll
            for (int iw = 0; iw < IW; ++iw) acc[mt][iw] = (f32x4){0.f, 0.f, 0.f, 0.f};

        short8 nbh, nbl;
        if (ih == 0) {
            nbh = pbh; nbl = pbl;
        } else {
            size_t bi = (((size_t)(w * NT4 + ih * IW)) * 64 + lane) * 8;
            nbh = *(const short8*)(Bh + bi);
            nbl = *(const short8*)(Bl + bi);
        }
        #pragma unroll
        for (int ks = 0; ks < KS; ++ks) {
            short8 ah[4], al[4];
            #pragma unroll
            for (int mt = 0; mt < 4; ++mt) {
                int fo = ((mt * KS + ks) * 64 + lane) * 8;
                ah[mt] = *(const short8*)&AhF[fo];
                al[mt] = *(const short8*)&AlF[fo];
            }
            #pragma unroll
            for (int iw = 0; iw < IW; ++iw) {
                short8 bh = nbh, bl = nbl;
                if (!(ks == KS - 1 && iw == IW - 1)) {
                    int nks = (iw == IW - 1) ? ks + 1 : ks;
                    int niw = (iw == IW - 1) ? 0 : iw + 1;
                    size_t bi = (((size_t)(nks * NT + w * NT4 + ih * IW + niw)) * 64 + lane) * 8;
                    nbh = *(const short8*)(Bh + bi);
                    nbl = *(const short8*)(Bl + bi);
                }
                #pragma unroll
                for (int mt = 0; mt < 4; ++mt) {
                    acc[mt][iw] = __builtin_amdgcn_mfma_f32_16x16x32_bf16(ah[mt], bh, acc[mt][iw], 0, 0, 0);
                    acc[mt][iw] = __builtin_amdgcn_mfma_f32_16x16x32_bf16(ah[mt], bl, acc[mt][iw], 0, 0, 0);
                    acc[mt][iw] = __builtin_amdgcn_mfma_f32_16x16x32_bf16(al[mt], bh, acc[mt][iw], 0, 0, 0);
                }
            }
        }
        #pragma unroll
        for (int pt = 0; pt < PTS; ++pt) {
            size_t ni = (size_t)b * Np + n0 + pt;
            #pragma unroll
            for (int iw = 0; iw < IW; ++iw) {
                f32x4 a0 = acc[2 * pt][iw], a1 = acc[2 * pt + 1][iw];
                float m = fmaxf(fmaxf(fmaxf(a0[0], a0[1]), fmaxf(a0[2], a0[3])),
                                fmaxf(fmaxf(a1[0], a1[1]), fmaxf(a1[2], a1[3])));
                m = fmaxf(m, __shfl_xor(m, 16, 64));
                m = fmaxf(m, __shfl_xor(m, 32, 64));
                if (lane < 16) {
                    int o = (w * NT4 + ih * IW + iw) * 16 + col;
                    Ypm[ni * O + o] = lrelu(m + cb[ni * O + o]);
                }
            }
        }
    }
}

// Legacy fused EdgeConv for layer 1 (C=3)
template<int C, int CPAD, int O, int OPT, int KPT, int PTS>
__global__ __launch_bounds__(256) void k_edgeconv(
    const float* __restrict__ Xpm, const int* __restrict__ idxg,
    const float* __restrict__ W, const float* __restrict__ sg, const float* __restrict__ bg,
    float* __restrict__ Ypm)
{
    constexpr int OG = O / OPT;
    constexpr int NKG = 256 / OG;
    constexpr int CL = CPAD + 4;
    static_assert(NKG * KPT == Kn, "k mapping");
    __shared__ float nbr[PTS][Kn][CL];
    __shared__ float ctr[PTS][CPAD];
    __shared__ float red[PTS][OPT][4][OG];
    int blk = blockIdx.x;
    int b = blk / (Np / PTS);
    int n0 = (blk % (Np / PTS)) * PTS;
    int t = threadIdx.x;
    int lane = t & 63, wid = t >> 6;
    const int* ip = idxg + ((size_t)b * Np + n0) * Kn;
    const float4* Xp4 = (const float4*)Xpm;
    constexpr int C4 = CPAD / 4;
    for (int e = t; e < PTS * C4; e += 256) {
        int pt = e / C4, c4 = e % C4;
        *(float4*)&ctr[pt][4 * c4] = Xp4[((size_t)b * Np + n0 + pt) * C4 + c4];
    }
    for (int e = t; e < PTS * Kn * C4; e += 256) {
        int pt = e / (Kn * C4);
        int r = e % (Kn * C4);
        int k = r / C4, c4 = r % C4;
        int nb = ip[pt * Kn + k];
        *(float4*)&nbr[pt][k][4 * c4] = Xp4[((size_t)b * Np + nb) * C4 + c4];
    }
    __syncthreads();
    int og = t % OG, kg = t / OG;
    float acc[PTS][OPT][KPT] = {};
    float ctt[PTS][OPT] = {};
    for (int c0 = 0; c0 < CPAD; c0 += 4) {
        float wn[OPT][4], wd[OPT][4];
        #pragma unroll
        for (int p = 0; p < OPT; ++p) {
            #pragma unroll
            for (int cc = 0; cc < 4; ++cc) {
                int c = c0 + cc;
                float a = (c < C) ? W[(size_t)(og + p * OG) * (2 * C) + c] : 0.f;
                float q = (c < C) ? W[(size_t)(og + p * OG) * (2 * C) + C + c] : 0.f;
                wn[p][cc] = a; wd[p][cc] = q - a;
            }
        }
        #pragma unroll
        for (int pt = 0; pt < PTS; ++pt) {
            float4 cv = *(const float4*)&ctr[pt][c0];
            #pragma unroll
            for (int p = 0; p < OPT; ++p) {
                ctt[pt][p] = fmaf(wd[p][0], cv.x, ctt[pt][p]);
                ctt[pt][p] = fmaf(wd[p][1], cv.y, ctt[pt][p]);
                ctt[pt][p] = fmaf(wd[p][2], cv.z, ctt[pt][p]);
                ctt[pt][p] = fmaf(wd[p][3], cv.w, ctt[pt][p]);
            }
        }
        #pragma unroll
        for (int pt = 0; pt < PTS; ++pt) {
            #pragma unroll
            for (int k = 0; k < KPT; ++k) {
                float4 nv = *(const float4*)&nbr[pt][kg * KPT + k][c0];
                #pragma unroll
                for (int p = 0; p < OPT; ++p) {
                    acc[pt][p][k] = fmaf(wn[p][0], nv.x, acc[pt][p][k]);
                    acc[pt][p][k] = fmaf(wn[p][1], nv.y, acc[pt][p][k]);
                    acc[pt][p][k] = fmaf(wn[p][2], nv.z, acc[pt][p][k]);
                    acc[pt][p][k] = fmaf(wn[p][3], nv.w, acc[pt][p][k]);
                }
            }
        }
    }
    #pragma unroll
    for (int pt = 0; pt < PTS; ++pt) {
        #pragma unroll
        for (int p = 0; p < OPT; ++p) {
            int o = og + p * OG;
            float sv = sg[o], bv = bg[o];
            float m = -INFINITY;
            #pragma unroll
            for (int k = 0; k < KPT; ++k) {
                float hv = fmaf(acc[pt][p][k] + ctt[pt][p], sv, bv);
                m = fmaxf(m, lrelu(hv));
            }
            #pragma unroll
            for (int s = OG; s < 64; s <<= 1) m = fmaxf(m, __shfl_xor(m, s, 64));
            if (lane < OG) red[pt][p][wid][lane] = m;
        }
    }
    __syncthreads();
    if (t < OG) {
        #pragma unroll
        for (int pt = 0; pt < PTS; ++pt) {
            #pragma unroll
            for (int p = 0; p < OPT; ++p) {
                float m = fmaxf(fmaxf(red[pt][p][0][t], red[pt][p][1][t]),
                                fmaxf(red[pt][p][2][t], red[pt][p][3][t]));
                int o = t + p * OG;
                Ypm[((size_t)b * Np + n0 + pt) * O + o] = m;
            }
        }
    }
}

// MFMA W5 (K=512, O=1024) + bias + LeakyReLU + max/sum pool over 32 points -> partials.
__global__ __launch_bounds__(1024, 4) void k_w5mfma(
    const float* __restrict__ x1, const float* __restrict__ x2,
    const float* __restrict__ x3, const float* __restrict__ x4,
    const ushortT* __restrict__ Bh, const ushortT* __restrict__ Bl,
    const float* __restrict__ b5,
    float* __restrict__ pmax, float* __restrict__ psum)
{
    constexpr int CP = 520;                 // 512 + 8 pad
    extern __shared__ char smem[];
    ushortT* Ah = (ushortT*)smem;           // [32][CP]
    ushortT* Al = Ah + 32 * CP;             // [32][CP]
    int b = blockIdx.x >> 6;
    int chunk = blockIdx.x & 63;
    int n0 = chunk * 32;
    int t = threadIdx.x;
    for (int e = t; e < 32 * 128; e += 1024) {
        int pt = e >> 7, c4 = e & 127;
        size_t pi = (size_t)b * Np + n0 + pt;
        float4 v;
        if (c4 < 16)      v = ((const float4*)x1)[pi * 16 + c4];
        else if (c4 < 32) v = ((const float4*)x2)[pi * 16 + (c4 - 16)];
        else if (c4 < 64) v = ((const float4*)x3)[pi * 32 + (c4 - 32)];
        else              v = ((const float4*)x4)[pi * 64 + (c4 - 64)];
        unsigned h0, l0, h1, l1;
        cvt2u(v.x, v.y, h0, l0);
        cvt2u(v.z, v.w, h1, l1);
        *(uint2*)&Ah[pt * CP + 4 * c4] = make_uint2(h0, h1);
        *(uint2*)&Al[pt * CP + 4 * c4] = make_uint2(l0, l1);
    }
    __syncthreads();
    int w = t >> 6, lane = t & 63;
    int quad = lane >> 4, col = lane & 15;
    size_t pb = ((size_t)(b * 64 + chunk)) * 1024;
    for (int oi = 0; oi < 4; ++oi) {
        int nt = w * 4 + oi;
        f32x4 a0 = (f32x4){0.f, 0.f, 0.f, 0.f};
        f32x4 a1 = (f32x4){0.f, 0.f, 0.f, 0.f};
        #pragma unroll 2
        for (int ks = 0; ks < 16; ++ks) {
            size_t bi = (((size_t)(ks * 64 + nt)) * 64 + lane) * 8;
            short8 bh = *(const short8*)(Bh + bi);
            short8 bl = *(const short8*)(Bl + bi);
            int ao = ks * 32 + quad * 8;
            short8 ah0 = *(const short8*)&Ah[col * CP + ao];
            short8 al0 = *(const short8*)&Al[col * CP + ao];
            short8 ah1 = *(const short8*)&Ah[(16 + col) * CP + ao];
            short8 al1 = *(const short8*)&Al[(16 + col) * CP + ao];
            a0 = __builtin_amdgcn_mfma_f32_16x16x32_bf16(ah0, bh, a0, 0, 0, 0);
            a1 = __builtin_amdgcn_mfma_f32_16x16x32_bf16(ah1, bh, a1, 0, 0, 0);
            a0 = __builtin_amdgcn_mfma_f32_16x16x32_bf16(ah0, bl, a0, 0, 0, 0);
            a1 = __builtin_amdgcn_mfma_f32_16x16x32_bf16(ah1, bl, a1, 0, 0, 0);
            a0 = __builtin_amdgcn_mfma_f32_16x16x32_bf16(al0, bh, a0, 0, 0, 0);
            a1 = __builtin_amdgcn_mfma_f32_16x16x32_bf16(al1, bh, a1, 0, 0, 0);
        }
        float bb = b5[nt * 16 + col];
        float mx = -INFINITY, sm = 0.f;
        #pragma unroll
        for (int r = 0; r < 4; ++r) {
            float v0 = lrelu(a0[r] + bb);
            float v1 = lrelu(a1[r] + bb);
            mx = fmaxf(mx, fmaxf(v0, v1));
            sm += v0 + v1;
        }
        mx = fmaxf(mx, __shfl_xor(mx, 16, 64));
        mx = fmaxf(mx, __shfl_xor(mx, 32, 64));
        sm += __shfl_xor(sm, 16, 64);
        sm += __shfl_xor(sm, 32, 64);
        if (lane < 16) {
            pmax[pb + nt * 16 + col] = mx;
            psum[pb + nt * 16 + col] = sm;
        }
    }
}

__global__ __launch_bounds__(256) void k_poolred(const float* __restrict__ pmax, const float* __restrict__ psum,
                                                 float* __restrict__ g0) {
    int i = blockIdx.x * 256 + threadIdx.x;
    int b = i >> 10, o = i & 1023;
    float mx = -INFINITY, sm = 0.f;
    for (int ch = 0; ch < 64; ++ch) {
        size_t idx = ((size_t)(b * 64 + ch)) * 1024 + o;
        mx = fmaxf(mx, pmax[idx]);
        sm += psum[idx];
    }
    g0[(size_t)b * 2048 + o] = mx;
    g0[(size_t)b * 2048 + 1024 + o] = sm * (1.f / Np);
}

__global__ __launch_bounds__(256) void k_fc(const float* __restrict__ In, int ldIn, int C,
                                            const float* __restrict__ Wm,
                                            const float* __restrict__ bias,
                                            const float* __restrict__ sc, const float* __restrict__ bnb,
                                            int leaky, float* __restrict__ Out, int ldOut, int O) {
    int wid = threadIdx.x >> 6, lane = threadIdx.x & 63;
    int o = blockIdx.x * 4 + wid;
    int b = blockIdx.y;
    if (o >= O) return;
    const float* in = In + (size_t)b * ldIn;
    const float* wr = Wm + (size_t)o * C;
    float acc = 0.f;
    for (int c = lane; c < C; c += 64) acc = fmaf(in[c], wr[c], acc);
    #pragma unroll
    for (int off = 32; off; off >>= 1) acc += __shfl_down(acc, off, 64);
    if (lane == 0) {
        float v = acc + (bias ? bias[o] : 0.f);
        if (sc) v = fmaf(v, sc[o], bnb[o]);
        if (leaky) v = lrelu(v);
        Out[(size_t)b * ldOut + o] = v;
    }
}

extern "C" void kernel_launch(void* const* d_in, const int* in_sizes, int n_in,
                              void* d_out, int out_size, void* d_ws, size_t ws_size,
                              hipStream_t stream) {
    const float* x   = (const float*)d_in[0];
    const float* W1  = (const float*)d_in[1];
    const float* s1  = (const float*)d_in[2];
    const float* b1  = (const float*)d_in[3];
    const float* W2  = (const float*)d_in[4];
    const float* s2  = (const float*)d_in[5];
    const float* b2  = (const float*)d_in[6];
    const float* W3  = (const float*)d_in[7];
    const float* s3  = (const float*)d_in[8];
    const float* b3  = (const float*)d_in[9];
    const float* W4  = (const float*)d_in[10];
    const float* s4  = (const float*)d_in[11];
    const float* b4  = (const float*)d_in[12];
    const float* W5  = (const float*)d_in[13];
    const float* s5  = (const float*)d_in[14];
    const float* b5  = (const float*)d_in[15];
    const float* L1w = (const float*)d_in[16];
    const float* s6  = (const float*)d_in[17];
    const float* b6  = (const float*)d_in[18];
    const float* L2w = (const float*)d_in[19];
    const float* L2b = (const float*)d_in[20];
    const float* s7  = (const float*)d_in[21];
    const float* b7  = (const float*)d_in[22];
    const float* L3w = (const float*)d_in[23];
    const float* L3b = (const float*)d_in[24];
    const float* F1w = (const float*)d_in[25];
    const float* s8  = (const float*)d_in[26];
    const float* b8  = (const float*)d_in[27];
    const float* F2w = (const float*)d_in[28];
    const float* F2b = (const float*)d_in[29];
    const float* s9  = (const float*)d_in[30];
    const float* b9  = (const float*)d_in[31];
    const float* F3w = (const float*)d_in[32];
    const float* F3b = (const float*)d_in[33];

    float* ws = (float*)d_ws;
    size_t off = 0;
    auto alloc = [&](size_t n) { float* p = ws + off; off += n; return p; };
    float* pts  = alloc((size_t)Bn * Np * 4);
    float* x1   = alloc((size_t)Bn * Np * 64);
    float* x2   = alloc((size_t)Bn * Np * 64);
    float* x3   = alloc((size_t)Bn * Np * 128);
    float* x4   = alloc((size_t)Bn * Np * 256);
    float* xcm  = alloc((size_t)Bn * Np * 128);   // aliased: pmax / psum
    float* xxb  = alloc((size_t)Bn * Np);
    int*   idxb = (int*)alloc((size_t)Bn * Np * Kn);
    float* g0   = alloc((size_t)Bn * 2048);
    float* g1   = alloc((size_t)Bn * 512);
    float* g2   = alloc((size_t)Bn * 256);
    float* y1   = alloc((size_t)Bn * 512);
    float* y2   = alloc((size_t)Bn * 256);
    float* WnsT2 = alloc(64 * 64);
    float* WdsT2 = alloc(64 * 64);
    float* WnsT3 = alloc(64 * 128);
    float* WdsT3 = alloc(64 * 128);
    float* WnsT4 = alloc(128 * 256);
    float* WdsT4 = alloc(128 * 256);
    ushortT* Bh2 = (ushortT*)alloc(64 * 64 / 2);
    ushortT* Bl2 = (ushortT*)alloc(64 * 64 / 2);
    ushortT* Bh3 = (ushortT*)alloc(64 * 128 / 2);
    ushortT* Bl3 = (ushortT*)alloc(64 * 128 / 2);
    ushortT* Bh4 = (ushortT*)alloc(128 * 256 / 2);
    ushortT* Bl4 = (ushortT*)alloc(128 * 256 / 2);
    ushortT* BhK = (ushortT*)alloc(1048576);   // knn B-frag hi (max C=128: 2M shorts)
    ushortT* BlK = (ushortT*)alloc(1048576);
    ushortT* Bh5 = (ushortT*)alloc(262144);    // W5 frag hi: 512K shorts
    ushortT* Bl5 = (ushortT*)alloc(262144);
    float* pmax = xcm;
    float* psum = xcm + 524288;
    float* cb2 = x2;
    float* cb3 = x3;
    float* cb4 = x4;

    // dynamic-LDS opt-ins (idempotent, safe pre-capture)
    // dl is [16][514] f32 (4-pass column split)
    auto shsz = [](int CP) { return 16 * CP * 2 * 2 + 64 + 16 * 514 * 4; };
    int sh3 = shsz(40), sh64 = shsz(72), sh128 = shsz(136);
    int shw5 = 32 * 520 * 2 * 2;
    (void)hipFuncSetAttribute((const void*)k_knn5<3, 32, 4>, hipFuncAttributeMaxDynamicSharedMemorySize, sh3);
    (void)hipFuncSetAttribute((const void*)k_knn5<64, 64, 64>, hipFuncAttributeMaxDynamicSharedMemorySize, sh64);
    (void)hipFuncSetAttribute((const void*)k_knn5<128, 128, 128>, hipFuncAttributeMaxDynamicSharedMemorySize, sh128);
    (void)hipFuncSetAttribute((const void*)k_w5mfma, hipFuncAttributeMaxDynamicSharedMemorySize, shw5);

    k_transpose<<<Bn * Np / 256, 256, 0, stream>>>(x, pts);
    k_wsplit<<<16, 256, 0, stream>>>(W2, s2, 64, 64, WnsT2, WdsT2);
    k_wsplit<<<32, 256, 0, stream>>>(W3, s3, 64, 128, WnsT3, WdsT3);
    k_wsplit<<<128, 256, 0, stream>>>(W4, s4, 128, 256, WnsT4, WdsT4);
    k_wpack<<<2, 256, 0, stream>>>(W2, s2, 64, 64, Bh2, Bl2);
    k_wpack<<<4, 256, 0, stream>>>(W3, s3, 64, 128, Bh3, Bl3);
    k_wpack<<<16, 256, 0, stream>>>(W4, s4, 128, 256, Bh4, Bl4);
    k_w5pack<<<256, 256, 0, stream>>>(W5, s5, Bh5, Bl5);

    // Layer 1: C=3
    k_xx<<<Bn * Np / 4, 256, 0, stream>>>(pts, xxb, 3, 4);
    k_bpack<3, 32, 4><<<Bn * 1 * 32, 256, 0, stream>>>(pts, BhK, BlK);
    k_knn5<3, 32, 4><<<Bn * Np / 16, 1024, sh3, stream>>>(pts, BhK, BlK, xxb, idxb);
    k_edgeconv<3, 4, 64, 1, 8, 4><<<Bn * Np / 4, 256, 0, stream>>>(pts, idxb, W1, s1, b1, x1);

    // Layer 2: C=64 -> O=64
    k_xx<<<Bn * Np / 4, 256, 0, stream>>>(x1, xxb, 64, 64);
    k_bpack<64, 64, 64><<<Bn * 2 * 32, 256, 0, stream>>>(x1, BhK, BlK);
    k_knn5<64, 64, 64><<<Bn * Np / 16, 1024, sh64, stream>>>(x1, BhK, BlK, xxb, idxb);
    k_ctr<64, 64, 4><<<Bn * Np / 32, 256, 0, stream>>>(x1, WdsT2, b2, cb2);
    k_ec3<64, 64, 2><<<Bn * Np / 2, 256, 0, stream>>>(x1, idxb, Bh2, Bl2, cb2, x2);

    // Layer 3: C=64 -> O=128
    k_xx<<<Bn * Np / 4, 256, 0, stream>>>(x2, xxb, 64, 64);
    k_bpack<64, 64, 64><<<Bn * 2 * 32, 256, 0, stream>>>(x2, BhK, BlK);
    k_knn5<64, 64, 64><<<Bn * Np / 16, 1024, sh64, stream>>>(x2, BhK, BlK, xxb, idxb);
    k_ctr<64, 128, 8><<<Bn * Np / 32, 256, 0, stream>>>(x2, WdsT3, b3, cb3);
    k_ec3<64, 128, 2><<<Bn * Np / 2, 256, 0, stream>>>(x2, idxb, Bh3, Bl3, cb3, x3);

    // Layer 4: C=128 -> O=256
    k_xx<<<Bn * Np / 4, 256, 0, stream>>>(x3, xxb, 128, 128);
    k_bpack<128, 128, 128><<<Bn * 4 * 32, 256, 0, stream>>>(x3, BhK, BlK);
    k_knn5<128, 128, 128><<<Bn * Np / 16, 1024, sh128, stream>>>(x3, BhK, BlK, xxb, idxb);
    k_ctr<128, 256, 8><<<Bn * Np / 32, 256, 0, stream>>>(x3, WdsT4, b4, cb4);
    k_ec3<128, 256, 2><<<Bn * Np / 2, 256, 0, stream>>>(x3, idxb, Bh4, Bl4, cb4, x4);

    // W5 + pooling (MFMA, 16-wave blocks)
    k_w5mfma<<<Bn * 64, 1024, shw5, stream>>>(x1, x2, x3, x4, Bh5, Bl5, b5, pmax, psum);
    k_poolred<<<Bn * 1024 / 256, 256, 0, stream>>>(pmax, psum, g0);

    float* out = (float*)d_out;
    k_fc<<<dim3(128, Bn), 256, 0, stream>>>(g0, 2048, 2048, L1w, nullptr, s6, b6, 1, g1, 512, 512);
    k_fc<<<dim3(64, Bn), 256, 0, stream>>>(g1, 512, 512, L2w, L2b, s7, b7, 1, g2, 256, 256);
    k_fc<<<dim3(2, Bn), 256, 0, stream>>>(g2, 256, 256, L3w, L3b, nullptr, nullptr, 0, out, 5, 5);
    k_fc<<<dim3(128, Bn), 256, 0, stream>>>(g0, 2048, 1024, F1w, nullptr, s8, b8, 1, y1, 512, 512);
    k_fc<<<dim3(64, Bn), 256, 0, stream>>>(y1, 512, 512, F2w, F2b, s9, b9, 1, y2, 256, 256);
    k_fc<<<dim3(2, Bn), 256, 0, stream>>>(y2, 256, 256, F3w, F3b, nullptr, nullptr, 0, out + 40, 5, 5);
}

// Round 15
// 812.421 us; speedup vs baseline: 1.0068x; 1.0068x over previous
//
#include <hip/hip_runtime.h>
#include <math.h>

constexpr int Bn = 8;
constexpr int Np = 2048;
constexpr int Kn = 32;
constexpr float NEGS = 0.2f;

typedef __attribute__((ext_vector_type(8))) short short8;
typedef __attribute__((ext_vector_type(4))) float f32x4;
typedef unsigned short ushortT;

__device__ __forceinline__ float lrelu(float v) { return v > 0.f ? v : NEGS * v; }

// DPP-based max step; ctrl/rmask as template args (builtin requires ICE operands)
template<int CTRL, int RMASK>
__device__ __forceinline__ float dppmax(float v) {
    int o = __float_as_int(v);
    int s = __builtin_amdgcn_update_dpp(o, o, CTRL, RMASK, 0xf, false);
    return fmaxf(v, __int_as_float(s));
}
// full 64-lane max via DPP (valid in lane 63), then readlane-broadcast
__device__ __forceinline__ float wave_max_dpp(float v) {
    v = dppmax<0x111, 0xf>(v);   // row_shr:1
    v = dppmax<0x112, 0xf>(v);   // row_shr:2
    v = dppmax<0x114, 0xf>(v);   // row_shr:4
    v = dppmax<0x118, 0xf>(v);   // row_shr:8
    v = dppmax<0x142, 0xa>(v);   // row_bcast:15 -> rows 1,3
    v = dppmax<0x143, 0xc>(v);   // row_bcast:31 -> row 3 (and 2)
    return __int_as_float(__builtin_amdgcn_readlane(__float_as_int(v), 63));
}

// split fp32 -> bf16 hi (truncate) + bf16 lo (residual, truncate); packed 2-at-a-time
__device__ __forceinline__ void cvt2u(float a, float b, unsigned& h, unsigned& l) {
    unsigned ua = __float_as_uint(a), ub = __float_as_uint(b);
    h = (ua >> 16) | (ub & 0xffff0000u);
    float ra = a - __uint_as_float(ua & 0xffff0000u);
    float rb = b - __uint_as_float(ub & 0xffff0000u);
    l = (__float_as_uint(ra) >> 16) | (__float_as_uint(rb) & 0xffff0000u);
}

// x [B,3,N] -> pts point-major [B*N, 4] (pad lane = 0)
__global__ __launch_bounds__(256) void k_transpose(const float* __restrict__ x, float* __restrict__ pts) {
    int i = blockIdx.x * 256 + threadIdx.x;
    int b = i / Np, n = i % Np;
    float p0 = x[((size_t)b * 3 + 0) * Np + n];
    float p1 = x[((size_t)b * 3 + 1) * Np + n];
    float p2 = x[((size_t)b * 3 + 2) * Np + n];
    float4 v = make_float4(p0, p1, p2, 0.f);
    *(float4*)&pts[(size_t)i * 4] = v;
}

// xx[i] = sum_c pm[i*ld+c]^2 ; one wave per point, 4 points per block
__global__ __launch_bounds__(256) void k_xx(const float* __restrict__ pm, float* __restrict__ xxg, int C, int ld) {
    int wid = threadIdx.x >> 6, lane = threadIdx.x & 63;
    int pt = blockIdx.x * 4 + wid;
    const float* row = pm + (size_t)pt * ld;
    float acc = 0.f;
    for (int c = lane; c < C; c += 64) { float v = row[c]; acc = fmaf(v, v, acc); }
    #pragma unroll
    for (int off = 32; off; off >>= 1) acc += __shfl_down(acc, off, 64);
    if (lane == 0) xxg[pt] = acc;
}

// Pack points into mfma_16x16x32 B-fragment order (bf16 hi/lo), per batch.
// v2: 8-wide vectorized — one thread per (b,ks,nt,lane) handles j=0..7.
template<int C, int CK, int LD>
__global__ __launch_bounds__(256) void k_bpack(const float* __restrict__ Xpm,
                                               ushortT* __restrict__ Bh, ushortT* __restrict__ Bl) {
    constexpr int KS = CK / 32;
    int tid = blockIdx.x * 256 + threadIdx.x;   // Bn*KS*128*64 total
    int lane = tid & 63;
    int nt = (tid >> 6) & 127;
    int rest = tid >> 13;
    int ks = rest % KS;
    int b = rest / KS;
    int quad = lane >> 4;
    int n = nt * 16 + (lane & 15);
    int k0 = ks * 32 + quad * 8;
    size_t src = ((size_t)b * Np + n) * LD;
    unsigned h[4], l[4];
    if constexpr (LD >= 8) {
        const float4* p4 = (const float4*)(Xpm + src + k0);
        float4 va = p4[0], vb = p4[1];
        cvt2u(va.x, va.y, h[0], l[0]);
        cvt2u(va.z, va.w, h[1], l[1]);
        cvt2u(vb.x, vb.y, h[2], l[2]);
        cvt2u(vb.z, vb.w, h[3], l[3]);
    } else {
        float vv[8];
        #pragma unroll
        for (int j = 0; j < 8; ++j) {
            int k = k0 + j;
            vv[j] = (k < C) ? Xpm[src + k] : 0.f;
        }
        cvt2u(vv[0], vv[1], h[0], l[0]);
        cvt2u(vv[2], vv[3], h[1], l[1]);
        cvt2u(vv[4], vv[5], h[2], l[2]);
        cvt2u(vv[6], vv[7], h[3], l[3]);
    }
    size_t oi = (size_t)tid * 8;
    *(uint4*)&Bh[oi] = make_uint4(h[0], h[1], h[2], h[3]);
    *(uint4*)&Bl[oi] = make_uint4(l[0], l[1], l[2], l[3]);
}

// Distance compute for one column QUARTER (CC in 0..3, 512 columns each):
// wave w computes tiles ntl = w*2, w*2+1 (ng = CC*32 + ntl) -> dl in LDS.
template<int CC, int KS, int CPv, int SDv>
__device__ __forceinline__ void dist_compute(
    const ushortT* __restrict__ Ah, const ushortT* __restrict__ Al,
    float* __restrict__ dl, const float* __restrict__ xxg,
    const ushortT* __restrict__ Bh, const ushortT* __restrict__ Bl,
    int b, int w, int lane, int quad, int col,
    const float (&xmr)[4])
{
    short8 ah[KS], al[KS];
    #pragma unroll
    for (int ks = 0; ks < KS; ++ks) {
        ah[ks] = *(const short8*)&Ah[col * CPv + ks * 32 + quad * 8];
        al[ks] = *(const short8*)&Al[col * CPv + ks * 32 + quad * 8];
    }
    int ntl0 = w * 2, ntl1 = ntl0 + 1;
    int ng0 = CC * 32 + ntl0, ng1 = CC * 32 + ntl1;
    f32x4 a0 = (f32x4){0.f, 0.f, 0.f, 0.f};
    f32x4 a1 = (f32x4){0.f, 0.f, 0.f, 0.f};
    #pragma unroll
    for (int ks = 0; ks < KS; ++ks) {
        int bi0 = (((b * KS + ks) * 128 + ng0) * 64 + lane) * 8;
        int bi1 = (((b * KS + ks) * 128 + ng1) * 64 + lane) * 8;
        short8 bh0 = *(const short8*)(Bh + bi0);
        short8 bl0 = *(const short8*)(Bl + bi0);
        short8 bh1 = *(const short8*)(Bh + bi1);
        short8 bl1 = *(const short8*)(Bl + bi1);
        a0 = __builtin_amdgcn_mfma_f32_16x16x32_bf16(ah[ks], bh0, a0, 0, 0, 0);
        a1 = __builtin_amdgcn_mfma_f32_16x16x32_bf16(ah[ks], bh1, a1, 0, 0, 0);
        a0 = __builtin_amdgcn_mfma_f32_16x16x32_bf16(ah[ks], bl0, a0, 0, 0, 0);
        a1 = __builtin_amdgcn_mfma_f32_16x16x32_bf16(ah[ks], bl1, a1, 0, 0, 0);
        a0 = __builtin_amdgcn_mfma_f32_16x16x32_bf16(al[ks], bh0, a0, 0, 0, 0);
        a1 = __builtin_amdgcn_mfma_f32_16x16x32_bf16(al[ks], bh1, a1, 0, 0, 0);
    }
    float xn0 = xxg[b * Np + ng0 * 16 + col];
    float xn1 = xxg[b * Np + ng1 * 16 + col];
    #pragma unroll
    for (int r = 0; r < 4; ++r) {
        int m = quad * 4 + r;
        dl[m * SDv + ntl0 * 16 + col] = 2.f * a0[r] - xmr[r] - xn0;
        dl[m * SDv + ntl1 * 16 + col] = 2.f * a1[r] - xmr[r] - xn1;
    }
}

// MFMA kNN v12 (r12, FROZEN): 4-pass column split, dl=[16][514].
template<int C, int CK, int LD>
__global__ __launch_bounds__(1024) void k_knn5(const float* __restrict__ Xpm,
                                               const ushortT* __restrict__ Bh, const ushortT* __restrict__ Bl,
                                               const float* __restrict__ xxg, int* __restrict__ idxo) {
    constexpr int KS = CK / 32, CP = CK + 8, CK4 = CK / 4, C4src = LD / 4;
    constexpr int SD = 514;
    extern __shared__ char smem[];
    ushortT* Ah = (ushortT*)smem;              // [16][CP]
    ushortT* Al = Ah + 16 * CP;                // [16][CP]
    float* xxm = (float*)(Al + 16 * CP);       // [16]
    float* dl = xxm + 16;                      // [16][SD] distances (one column-quarter)
    int nwg = gridDim.x;
    int cpx = nwg >> 3;                        // 128 when nwg=1024
    int logical = (blockIdx.x & 7) * cpx + (blockIdx.x >> 3);
    int b = logical / (Np / 16);
    int n0 = (logical % (Np / 16)) * 16;
    int t = threadIdx.x;
    const float4* Xp4 = (const float4*)Xpm;
    for (int e = t; e < 16 * CK4; e += 1024) {
        int r = e / CK4, c4 = e % CK4;
        float4 v = (c4 < C4src) ? Xp4[((size_t)b * Np + n0 + r) * C4src + c4] : make_float4(0.f, 0.f, 0.f, 0.f);
        unsigned h0, l0, h1, l1;
        cvt2u(v.x, v.y, h0, l0);
        cvt2u(v.z, v.w, h1, l1);
        *(uint2*)&Ah[r * CP + 4 * c4] = make_uint2(h0, h1);
        *(uint2*)&Al[r * CP + 4 * c4] = make_uint2(l0, l1);
    }
    if (t < 16) xxm[t] = xxg[b * Np + t + n0];
    __syncthreads();

    int w = t >> 6, lane = t & 63;
    int quad = lane >> 4, col = lane & 15;
    float xmr[4];
    #pragma unroll
    for (int r = 0; r < 4; ++r) xmr[r] = xxm[quad * 4 + r];

    const float* drow = dl + w * SD;
    float v0, v1, v2, v3, v4, v5, v6, v7, v8, v9, v10, v11, v12, v13, v14, v15;
    float v16, v17, v18, v19, v20, v21, v22, v23, v24, v25, v26, v27, v28, v29, v30, v31;

    dist_compute<0, KS, CP, SD>(Ah, Al, dl, xxg, Bh, Bl, b, w, lane, quad, col, xmr);
    __syncthreads();
    v0 = drow[lane + 0 * 64]; v1 = drow[lane + 1 * 64];
    v2 = drow[lane + 2 * 64]; v3 = drow[lane + 3 * 64];
    v4 = drow[lane + 4 * 64]; v5 = drow[lane + 5 * 64];
    v6 = drow[lane + 6 * 64]; v7 = drow[lane + 7 * 64];
    __syncthreads();
    dist_compute<1, KS, CP, SD>(Ah, Al, dl, xxg, Bh, Bl, b, w, lane, quad, col, xmr);
    __syncthreads();
    v8  = drow[lane + 0 * 64]; v9  = drow[lane + 1 * 64];
    v10 = drow[lane + 2 * 64]; v11 = drow[lane + 3 * 64];
    v12 = drow[lane + 4 * 64]; v13 = drow[lane + 5 * 64];
    v14 = drow[lane + 6 * 64]; v15 = drow[lane + 7 * 64];
    __syncthreads();
    dist_compute<2, KS, CP, SD>(Ah, Al, dl, xxg, Bh, Bl, b, w, lane, quad, col, xmr);
    __syncthreads();
    v16 = drow[lane + 0 * 64]; v17 = drow[lane + 1 * 64];
    v18 = drow[lane + 2 * 64]; v19 = drow[lane + 3 * 64];
    v20 = drow[lane + 4 * 64]; v21 = drow[lane + 5 * 64];
    v22 = drow[lane + 6 * 64]; v23 = drow[lane + 7 * 64];
    __syncthreads();
    dist_compute<3, KS, CP, SD>(Ah, Al, dl, xxg, Bh, Bl, b, w, lane, quad, col, xmr);
    __syncthreads();
    v24 = drow[lane + 0 * 64]; v25 = drow[lane + 1 * 64];
    v26 = drow[lane + 2 * 64]; v27 = drow[lane + 3 * 64];
    v28 = drow[lane + 4 * 64]; v29 = drow[lane + 5 * 64];
    v30 = drow[lane + 6 * 64]; v31 = drow[lane + 7 * 64];

    // ---- selection: per-lane sorted top-4 (val,idx) list ----
    float s0v = -INFINITY, s1v = -INFINITY, s2v = -INFINITY, s3v = -INFINITY;
    int s0i = 0, s1i = 0, s2i = 0, s3i = 0;

#define INS4(VV, JJ) { \
    bool b0 = (VV) > s0v, b1 = (VV) > s1v, b2 = (VV) > s2v, b3 = (VV) > s3v; \
    s3v = b2 ? s2v : (b3 ? (VV) : s3v);  s3i = b2 ? s2i : (b3 ? (JJ) : s3i); \
    s2v = b1 ? s1v : (b2 ? (VV) : s2v);  s2i = b1 ? s1i : (b2 ? (JJ) : s2i); \
    s1v = b0 ? s0v : (b1 ? (VV) : s1v);  s1i = b0 ? s0i : (b1 ? (JJ) : s1i); \
    s0v = b0 ? (VV) : s0v;               s0i = b0 ? (JJ) : s0i; \
}
    INS4(v0, 0)   INS4(v1, 1)   INS4(v2, 2)   INS4(v3, 3)
    INS4(v4, 4)   INS4(v5, 5)   INS4(v6, 6)   INS4(v7, 7)
    INS4(v8, 8)   INS4(v9, 9)   INS4(v10, 10) INS4(v11, 11)
    INS4(v12, 12) INS4(v13, 13) INS4(v14, 14) INS4(v15, 15)
    INS4(v16, 16) INS4(v17, 17) INS4(v18, 18) INS4(v19, 19)
    INS4(v20, 20) INS4(v21, 21) INS4(v22, 22) INS4(v23, 23)
    INS4(v24, 24) INS4(v25, 25) INS4(v26, 26) INS4(v27, 27)
    INS4(v28, 28) INS4(v29, 29) INS4(v30, 30) INS4(v31, 31)

    unsigned umask = 0u;
    int pops = 0;
    size_t ob = ((size_t)b * Np + n0 + w) * Kn;
    for (int it = 0; it < Kn; ++it) {
        float Wv = wave_max_dpp(s0v);
        unsigned long long mk = __ballot(s0v == Wv);
        int owner = __ffsll(mk) - 1;
        bool pred = (lane == owner);
        if (pred) idxo[ob + it] = lane + (s0i << 6);
        umask |= pred ? (1u << s0i) : 0u;
        pops = pred ? (pops + 1) : pops;
        s0v = pred ? s1v : s0v;  s0i = pred ? s1i : s0i;
        s1v = pred ? s2v : s1v;  s1i = pred ? s2i : s1i;
        s2v = pred ? s3v : s2v;  s2i = pred ? s3i : s2i;
        s3v = pred ? -INFINITY : s3v;
        bool need = pred && (pops >= 4);
        if (__ballot(need)) {          // wave-uniform scalar branch, ~never taken
            if (need) {
                pops = 0;
                s0v = s1v = s2v = s3v = -INFINITY;
                s0i = s1i = s2i = s3i = 0;
#define RINS(VV, JJ) { float vv_ = ((umask >> (JJ)) & 1u) ? -INFINITY : (VV); INS4(vv_, JJ) }
                RINS(v0, 0)   RINS(v1, 1)   RINS(v2, 2)   RINS(v3, 3)
                RINS(v4, 4)   RINS(v5, 5)   RINS(v6, 6)   RINS(v7, 7)
                RINS(v8, 8)   RINS(v9, 9)   RINS(v10, 10) RINS(v11, 11)
                RINS(v12, 12) RINS(v13, 13) RINS(v14, 14) RINS(v15, 15)
                RINS(v16, 16) RINS(v17, 17) RINS(v18, 18) RINS(v19, 19)
                RINS(v20, 20) RINS(v21, 21) RINS(v22, 22) RINS(v23, 23)
                RINS(v24, 24) RINS(v25, 25) RINS(v26, 26) RINS(v27, 27)
                RINS(v28, 28) RINS(v29, 29) RINS(v30, 30) RINS(v31, 31)
#undef RINS
            }
        }
    }
#undef INS4
}

// W split+scale+transpose (fp32, for k_ctr): WdsT[c][o] = (W[o][C+c]-W[o][c])*s[o]
__global__ __launch_bounds__(256) void k_wsplit(const float* __restrict__ W, const float* __restrict__ s,
                                                int C, int O, float* __restrict__ WnsT, float* __restrict__ WdsT) {
    int i = blockIdx.x * 256 + threadIdx.x;
    if (i >= C * O) return;
    int c = i / O, o = i % O;
    float a = W[(size_t)o * 2 * C + c];
    float q = W[(size_t)o * 2 * C + C + c];
    float sv = s[o];
    WnsT[i] = a * sv;
    WdsT[i] = (q - a) * sv;
}

// Pack neighbor-half of W (scaled) into mfma_16x16x32 B-fragment order, split bf16 hi/lo.
// v2: 8-wide vectorized.
__global__ __launch_bounds__(256) void k_wpack(const float* __restrict__ W, const float* __restrict__ s,
                                               int C, int O, ushortT* __restrict__ Bh, ushortT* __restrict__ Bl) {
    int tid = blockIdx.x * 256 + threadIdx.x;   // C*O/8 total
    if (tid >= (C * O) / 8) return;
    int lane = tid & 63;
    int nt = tid >> 6;                          // ks*NT + nt combined
    int NT = O / 16;
    int ks = nt / NT;
    nt = nt % NT;
    int quad = lane >> 4;
    int o = nt * 16 + (lane & 15);
    int k0 = ks * 32 + quad * 8;
    const float* wr = W + (size_t)o * 2 * C + k0;
    float4 va = *(const float4*)wr;
    float4 vb = *(const float4*)(wr + 4);
    float sv = s[o];
    unsigned h[4], l[4];
    cvt2u(va.x * sv, va.y * sv, h[0], l[0]);
    cvt2u(va.z * sv, va.w * sv, h[1], l[1]);
    cvt2u(vb.x * sv, vb.y * sv, h[2], l[2]);
    cvt2u(vb.z * sv, vb.w * sv, h[3], l[3]);
    size_t oi = (size_t)tid * 8;
    *(uint4*)&Bh[oi] = make_uint4(h[0], h[1], h[2], h[3]);
    *(uint4*)&Bl[oi] = make_uint4(l[0], l[1], l[2], l[3]);
}

// Pack W5 (scaled by s5) [1024][512] into fragment order: KS=16, NT=64.
// v2: 8-wide vectorized.
__global__ __launch_bounds__(256) void k_w5pack(const float* __restrict__ W5, const float* __restrict__ s5,
                                                ushortT* __restrict__ Bh, ushortT* __restrict__ Bl) {
    int tid = blockIdx.x * 256 + threadIdx.x;   // 64K total
    int lane = tid & 63;
    int nt = (tid >> 6) & 63;
    int ks = tid >> 12;
    int quad = lane >> 4;
    int o = nt * 16 + (lane & 15);
    int k0 = ks * 32 + quad * 8;
    const float* wr = W5 + (size_t)o * 512 + k0;
    float4 va = *(const float4*)wr;
    float4 vb = *(const float4*)(wr + 4);
    float sv = s5[o];
    unsigned h[4], l[4];
    cvt2u(va.x * sv, va.y * sv, h[0], l[0]);
    cvt2u(va.z * sv, va.w * sv, h[1], l[1]);
    cvt2u(vb.x * sv, vb.y * sv, h[2], l[2]);
    cvt2u(vb.z * sv, vb.w * sv, h[3], l[3]);
    size_t oi = (size_t)tid * 8;
    *(uint4*)&Bh[oi] = make_uint4(h[0], h[1], h[2], h[3]);
    *(uint4*)&Bl[oi] = make_uint4(l[0], l[1], l[2], l[3]);
}

// cb[n][o] = sum_c ctr[n][c]*WdsT[c][o] + b[o].  32 points per block.
template<int C, int O, int OPT>
__global__ __launch_bounds__(256) void k_ctr(const float* __restrict__ Xpm, const float* __restrict__ WdsT,
                                             const float* __restrict__ bg, float* __restrict__ cb) {
    constexpr int OG = O / OPT, MG = 256 / OG, MPT = 32 / MG;
    constexpr int C4 = C / 4;
    __shared__ float xs[32][C];
    int b = blockIdx.x / (Np / 32);
    int n0 = (blockIdx.x % (Np / 32)) * 32;
    int t = threadIdx.x;
    const float4* Xp4 = (const float4*)Xpm;
    for (int e = t; e < 32 * C4; e += 256) {
        int pt = e / C4, c4 = e % C4;
        *(float4*)&xs[pt][4 * c4] = Xp4[((size_t)b * Np + n0 + pt) * C4 + c4];
    }
    __syncthreads();
    int og = t % OG, mg = t / OG;
    int o0 = og * OPT;
    float acc[MPT][OPT] = {};
    for (int c = 0; c < C; ++c) {
        float wv[OPT];
        #pragma unroll
        for (int p4 = 0; p4 < OPT / 4; ++p4)
            *(float4*)&wv[4 * p4] = *(const float4*)&WdsT[(size_t)c * O + o0 + 4 * p4];
        #pragma unroll
        for (int m = 0; m < MPT; ++m) {
            float xv = xs[mg * MPT + m][c];
            #pragma unroll
            for (int p = 0; p < OPT; ++p) acc[m][p] = fmaf(wv[p], xv, acc[m][p]);
        }
    }
    #pragma unroll
    for (int m = 0; m < MPT; ++m) {
        #pragma unroll
        for (int p = 0; p < OPT; ++p) {
            int o = o0 + p;
            cb[((size_t)b * Np + n0 + mg * MPT + m) * O + o] = acc[m][p] + bg[o];
        }
    }
}

// MFMA EdgeConv GEMM v7 (r13, FROZEN = session best 813.2us):
// fragment-linear LDS A (0 bank conflicts), launch_bounds(256,4),
// ks=0 B prefetch hoisted, T14 staging split (issue all loads then cvt).
// DO NOT raise min-waves: gfx950 wave-slot occupancy steps at VGPR
// 64/128/256 — min-5 forces ~64-reg budget incl. unified AGPR accs ->
// catastrophic scratch spill (r7: 860MB, r9: 893MB WRITE_SIZE).
// XCD swizzle tested r14: FETCH 41.5->13.9MB but dur unchanged (gather
// latency not on critical path) — reverted to best-measured config.
template<int C, int O, int PTS>
__global__ __launch_bounds__(256, 4) void k_ec3(const float* __restrict__ Xpm, const int* __restrict__ idxg,
                                                const ushortT* __restrict__ Bh, const ushortT* __restrict__ Bl,
                                                const float* __restrict__ cb,
                                                float* __restrict__ Ypm) {
    static_assert(PTS == 2, "M=64 mapping");
    constexpr int M = 64, NT = O / 16, NT4 = NT / 4, KS = C / 32, C4 = C / 4;
    constexpr int IH = (NT4 > 2) ? 2 : 1, IW = NT4 / IH;
    static_assert(NT4 >= 1, "O>=64");
    // A in fragment-linear order: [(mt*KS+ks)*64 + lane] * 8 shorts
    __shared__ ushortT AhF[M * C];
    __shared__ ushortT AlF[M * C];
    int b = blockIdx.x / (Np / PTS);
    int n0 = (blockIdx.x % (Np / PTS)) * PTS;
    int t = threadIdx.x;
    int w = t >> 6, lane = t & 63;
    int quad = lane >> 4, col = lane & 15;
    const int* ip = idxg + ((size_t)b * Np + n0) * Kn;
    const float4* Xp4 = (const float4*)Xpm;

    // early B prefetch (ih=0, ks=0) — in flight during A staging
    size_t b00 = (((size_t)(w * NT4)) * 64 + lane) * 8;
    short8 pbh = *(const short8*)(Bh + b00);
    short8 pbl = *(const short8*)(Bl + b00);

    // T14 staging: issue ALL global A-gather loads, then cvt+LDS-write.
    // wave w stages rows w*16 .. w*16+15 (mt = w), fragment-linear:
    // lane (quad,col) holds row w*16+col, k-slice quad*8 within each ks.
    int grow = ip[w * 16 + col];
    size_t gbase = ((size_t)b * Np + grow) * C4;
    float4 va[KS], vb[KS];
    #pragma unroll
    for (int ks = 0; ks < KS; ++ks) {
        int c4a = (ks * 32 + quad * 8) >> 2;
        va[ks] = Xp4[gbase + c4a];
        vb[ks] = Xp4[gbase + c4a + 1];
    }
    #pragma unroll
    for (int ks = 0; ks < KS; ++ks) {
        unsigned h0, l0, h1, l1, h2, l2, h3, l3;
        cvt2u(va[ks].x, va[ks].y, h0, l0);
        cvt2u(va[ks].z, va[ks].w, h1, l1);
        cvt2u(vb[ks].x, vb[ks].y, h2, l2);
        cvt2u(vb[ks].z, vb[ks].w, h3, l3);
        int fo = ((w * KS + ks) * 64 + lane) * 8;
        *(uint4*)&AhF[fo] = make_uint4(h0, h1, h2, h3);
        *(uint4*)&AlF[fo] = make_uint4(l0, l1, l2, l3);
    }
    __syncthreads();

    #pragma unroll
    for (int ih = 0; ih < IH; ++ih) {
        f32x4 acc[4][IW];
        #pragma unroll
        for (int mt = 0; mt < 4; ++mt)
            #pragma unroll
            for (int iw = 0; iw < IW; ++iw) acc[mt][iw] = (f32x4){0.f, 0.f, 0.f, 0.f};

        short8 nbh, nbl;
        if (ih == 0) {
            nbh = pbh; nbl = pbl;
        } else {
            size_t bi = (((size_t)(w * NT4 + ih * IW)) * 64 + lane) * 8;
            nbh = *(const short8*)(Bh + bi);
            nbl = *(const short8*)(Bl + bi);
        }
        #pragma unroll
        for (int ks = 0; ks < KS; ++ks) {
            short8 ah[4], al[4];
            #pragma unroll
            for (int mt = 0; mt < 4; ++mt) {
                int fo = ((mt * KS + ks) * 64 + lane) * 8;
                ah[mt] = *(const short8*)&AhF[fo];
                al[mt] = *(const short8*)&AlF[fo];
            }
            #pragma unroll
            for (int iw = 0; iw < IW; ++iw) {
                short8 bh = nbh, bl = nbl;
                if (!(ks == KS - 1 && iw == IW - 1)) {
                    int nks = (iw == IW - 1) ? ks + 1 : ks;
                    int niw = (iw == IW - 1) ? 0 : iw + 1;
                    size_t bi = (((size_t)(nks * NT + w * NT4 + ih * IW + niw)) * 64 + lane) * 8;
                    nbh = *(const short8*)(Bh + bi);
                    nbl = *(const short8*)(Bl + bi);
                }
                #pragma unroll
                for (int mt = 0; mt < 4; ++mt) {
                    acc[mt][iw] = __builtin_amdgcn_mfma_f32_16x16x32_bf16(ah[mt], bh, acc[mt][iw], 0, 0, 0);
                    acc[mt][iw] = __builtin_amdgcn_mfma_f32_16x16x32_bf16(ah[mt], bl, acc[mt][iw], 0, 0, 0);
                    acc[mt][iw] = __builtin_amdgcn_mfma_f32_16x16x32_bf16(al[mt], bh, acc[mt][iw], 0, 0, 0);
                }
            }
        }
        #pragma unroll
        for (int pt = 0; pt < PTS; ++pt) {
            size_t ni = (size_t)b * Np + n0 + pt;
            #pragma unroll
            for (int iw = 0; iw < IW; ++iw) {
                f32x4 a0 = acc[2 * pt][iw], a1 = acc[2 * pt + 1][iw];
                float m = fmaxf(fmaxf(fmaxf(a0[0], a0[1]), fmaxf(a0[2], a0[3])),
                                fmaxf(fmaxf(a1[0], a1[1]), fmaxf(a1[2], a1[3])));
                m = fmaxf(m, __shfl_xor(m, 16, 64));
                m = fmaxf(m, __shfl_xor(m, 32, 64));
                if (lane < 16) {
                    int o = (w * NT4 + ih * IW + iw) * 16 + col;
                    Ypm[ni * O + o] = lrelu(m + cb[ni * O + o]);
                }
            }
        }
    }
}

// Legacy fused EdgeConv for layer 1 (C=3)
template<int C, int CPAD, int O, int OPT, int KPT, int PTS>
__global__ __launch_bounds__(256) void k_edgeconv(
    const float* __restrict__ Xpm, const int* __restrict__ idxg,
    const float* __restrict__ W, const float* __restrict__ sg, const float* __restrict__ bg,
    float* __restrict__ Ypm)
{
    constexpr int OG = O / OPT;
    constexpr int NKG = 256 / OG;
    constexpr int CL = CPAD + 4;
    static_assert(NKG * KPT == Kn, "k mapping");
    __shared__ float nbr[PTS][Kn][CL];
    __shared__ float ctr[PTS][CPAD];
    __shared__ float red[PTS][OPT][4][OG];
    int blk = blockIdx.x;
    int b = blk / (Np / PTS);
    int n0 = (blk % (Np / PTS)) * PTS;
    int t = threadIdx.x;
    int lane = t & 63, wid = t >> 6;
    const int* ip = idxg + ((size_t)b * Np + n0) * Kn;
    const float4* Xp4 = (const float4*)Xpm;
    constexpr int C4 = CPAD / 4;
    for (int e = t; e < PTS * C4; e += 256) {
        int pt = e / C4, c4 = e % C4;
        *(float4*)&ctr[pt][4 * c4] = Xp4[((size_t)b * Np + n0 + pt) * C4 + c4];
    }
    for (int e = t; e < PTS * Kn * C4; e += 256) {
        int pt = e / (Kn * C4);
        int r = e % (Kn * C4);
        int k = r / C4, c4 = r % C4;
        int nb = ip[pt * Kn + k];
        *(float4*)&nbr[pt][k][4 * c4] = Xp4[((size_t)b * Np + nb) * C4 + c4];
    }
    __syncthreads();
    int og = t % OG, kg = t / OG;
    float acc[PTS][OPT][KPT] = {};
    float ctt[PTS][OPT] = {};
    for (int c0 = 0; c0 < CPAD; c0 += 4) {
        float wn[OPT][4], wd[OPT][4];
        #pragma unroll
        for (int p = 0; p < OPT; ++p) {
            #pragma unroll
            for (int cc = 0; cc < 4; ++cc) {
                int c = c0 + cc;
                float a = (c < C) ? W[(size_t)(og + p * OG) * (2 * C) + c] : 0.f;
                float q = (c < C) ? W[(size_t)(og + p * OG) * (2 * C) + C + c] : 0.f;
                wn[p][cc] = a; wd[p][cc] = q - a;
            }
        }
        #pragma unroll
        for (int pt = 0; pt < PTS; ++pt) {
            float4 cv = *(const float4*)&ctr[pt][c0];
            #pragma unroll
            for (int p = 0; p < OPT; ++p) {
                ctt[pt][p] = fmaf(wd[p][0], cv.x, ctt[pt][p]);
                ctt[pt][p] = fmaf(wd[p][1], cv.y, ctt[pt][p]);
                ctt[pt][p] = fmaf(wd[p][2], cv.z, ctt[pt][p]);
                ctt[pt][p] = fmaf(wd[p][3], cv.w, ctt[pt][p]);
            }
        }
        #pragma unroll
        for (int pt = 0; pt < PTS; ++pt) {
            #pragma unroll
            for (int k = 0; k < KPT; ++k) {
                float4 nv = *(const float4*)&nbr[pt][kg * KPT + k][c0];
                #pragma unroll
                for (int p = 0; p < OPT; ++p) {
                    acc[pt][p][k] = fmaf(wn[p][0], nv.x, acc[pt][p][k]);
                    acc[pt][p][k] = fmaf(wn[p][1], nv.y, acc[pt][p][k]);
                    acc[pt][p][k] = fmaf(wn[p][2], nv.z, acc[pt][p][k]);
                    acc[pt][p][k] = fmaf(wn[p][3], nv.w, acc[pt][p][k]);
                }
            }
        }
    }
    #pragma unroll
    for (int pt = 0; pt < PTS; ++pt) {
        #pragma unroll
        for (int p = 0; p < OPT; ++p) {
            int o = og + p * OG;
            float sv = sg[o], bv = bg[o];
            float m = -INFINITY;
            #pragma unroll
            for (int k = 0; k < KPT; ++k) {
                float hv = fmaf(acc[pt][p][k] + ctt[pt][p], sv, bv);
                m = fmaxf(m, lrelu(hv));
            }
            #pragma unroll
            for (int s = OG; s < 64; s <<= 1) m = fmaxf(m, __shfl_xor(m, s, 64));
            if (lane < OG) red[pt][p][wid][lane] = m;
        }
    }
    __syncthreads();
    if (t < OG) {
        #pragma unroll
        for (int pt = 0; pt < PTS; ++pt) {
            #pragma unroll
            for (int p = 0; p < OPT; ++p) {
                float m = fmaxf(fmaxf(red[pt][p][0][t], red[pt][p][1][t]),
                                fmaxf(red[pt][p][2][t], red[pt][p][3][t]));
                int o = t + p * OG;
                Ypm[((size_t)b * Np + n0 + pt) * O + o] = m;
            }
        }
    }
}

// MFMA W5 (K=512, O=1024) + bias + LeakyReLU + max/sum pool over 32 points -> partials.
__global__ __launch_bounds__(1024, 4) void k_w5mfma(
    const float* __restrict__ x1, const float* __restrict__ x2,
    const float* __restrict__ x3, const float* __restrict__ x4,
    const ushortT* __restrict__ Bh, const ushortT* __restrict__ Bl,
    const float* __restrict__ b5,
    float* __restrict__ pmax, float* __restrict__ psum)
{
    constexpr int CP = 520;                 // 512 + 8 pad
    extern __shared__ char smem[];
    ushortT* Ah = (ushortT*)smem;           // [32][CP]
    ushortT* Al = Ah + 32 * CP;             // [32][CP]
    int b = blockIdx.x >> 6;
    int chunk = blockIdx.x & 63;
    int n0 = chunk * 32;
    int t = threadIdx.x;
    for (int e = t; e < 32 * 128; e += 1024) {
        int pt = e >> 7, c4 = e & 127;
        size_t pi = (size_t)b * Np + n0 + pt;
        float4 v;
        if (c4 < 16)      v = ((const float4*)x1)[pi * 16 + c4];
        else if (c4 < 32) v = ((const float4*)x2)[pi * 16 + (c4 - 16)];
        else if (c4 < 64) v = ((const float4*)x3)[pi * 32 + (c4 - 32)];
        else              v = ((const float4*)x4)[pi * 64 + (c4 - 64)];
        unsigned h0, l0, h1, l1;
        cvt2u(v.x, v.y, h0, l0);
        cvt2u(v.z, v.w, h1, l1);
        *(uint2*)&Ah[pt * CP + 4 * c4] = make_uint2(h0, h1);
        *(uint2*)&Al[pt * CP + 4 * c4] = make_uint2(l0, l1);
    }
    __syncthreads();
    int w = t >> 6, lane = t & 63;
    int quad = lane >> 4, col = lane & 15;
    size_t pb = ((size_t)(b * 64 + chunk)) * 1024;
    for (int oi = 0; oi < 4; ++oi) {
        int nt = w * 4 + oi;
        f32x4 a0 = (f32x4){0.f, 0.f, 0.f, 0.f};
        f32x4 a1 = (f32x4){0.f, 0.f, 0.f, 0.f};
        #pragma unroll 2
        for (int ks = 0; ks < 16; ++ks) {
            size_t bi = (((size_t)(ks * 64 + nt)) * 64 + lane) * 8;
            short8 bh = *(const short8*)(Bh + bi);
            short8 bl = *(const short8*)(Bl + bi);
            int ao = ks * 32 + quad * 8;
            short8 ah0 = *(const short8*)&Ah[col * CP + ao];
            short8 al0 = *(const short8*)&Al[col * CP + ao];
            short8 ah1 = *(const short8*)&Ah[(16 + col) * CP + ao];
            short8 al1 = *(const short8*)&Al[(16 + col) * CP + ao];
            a0 = __builtin_amdgcn_mfma_f32_16x16x32_bf16(ah0, bh, a0, 0, 0, 0);
            a1 = __builtin_amdgcn_mfma_f32_16x16x32_bf16(ah1, bh, a1, 0, 0, 0);
            a0 = __builtin_amdgcn_mfma_f32_16x16x32_bf16(ah0, bl, a0, 0, 0, 0);
            a1 = __builtin_amdgcn_mfma_f32_16x16x32_bf16(ah1, bl, a1, 0, 0, 0);
            a0 = __builtin_amdgcn_mfma_f32_16x16x32_bf16(al0, bh, a0, 0, 0, 0);
            a1 = __builtin_amdgcn_mfma_f32_16x16x32_bf16(al1, bh, a1, 0, 0, 0);
        }
        float bb = b5[nt * 16 + col];
        float mx = -INFINITY, sm = 0.f;
        #pragma unroll
        for (int r = 0; r < 4; ++r) {
            float v0 = lrelu(a0[r] + bb);
            float v1 = lrelu(a1[r] + bb);
            mx = fmaxf(mx, fmaxf(v0, v1));
            sm += v0 + v1;
        }
        mx = fmaxf(mx, __shfl_xor(mx, 16, 64));
        mx = fmaxf(mx, __shfl_xor(mx, 32, 64));
        sm += __shfl_xor(sm, 16, 64);
        sm += __shfl_xor(sm, 32, 64);
        if (lane < 16) {
            pmax[pb + nt * 16 + col] = mx;
            psum[pb + nt * 16 + col] = sm;
        }
    }
}

__global__ __launch_bounds__(256) void k_poolred(const float* __restrict__ pmax, const float* __restrict__ psum,
                                                 float* __restrict__ g0) {
    int i = blockIdx.x * 256 + threadIdx.x;
    int b = i >> 10, o = i & 1023;
    float mx = -INFINITY, sm = 0.f;
    for (int ch = 0; ch < 64; ++ch) {
        size_t idx = ((size_t)(b * 64 + ch)) * 1024 + o;
        mx = fmaxf(mx, pmax[idx]);
        sm += psum[idx];
    }
    g0[(size_t)b * 2048 + o] = mx;
    g0[(size_t)b * 2048 + 1024 + o] = sm * (1.f / Np);
}

__global__ __launch_bounds__(256) void k_fc(const float* __restrict__ In, int ldIn, int C,
                                            const float* __restrict__ Wm,
                                            const float* __restrict__ bias,
                                            const float* __restrict__ sc, const float* __restrict__ bnb,
                                            int leaky, float* __restrict__ Out, int ldOut, int O) {
    int wid = threadIdx.x >> 6, lane = threadIdx.x & 63;
    int o = blockIdx.x * 4 + wid;
    int b = blockIdx.y;
    if (o >= O) return;
    const float* in = In + (size_t)b * ldIn;
    const float* wr = Wm + (size_t)o * C;
    float acc = 0.f;
    for (int c = lane; c < C; c += 64) acc = fmaf(in[c], wr[c], acc);
    #pragma unroll
    for (int off = 32; off; off >>= 1) acc += __shfl_down(acc, off, 64);
    if (lane == 0) {
        float v = acc + (bias ? bias[o] : 0.f);
        if (sc) v = fmaf(v, sc[o], bnb[o]);
        if (leaky) v = lrelu(v);
        Out[(size_t)b * ldOut + o] = v;
    }
}

extern "C" void kernel_launch(void* const* d_in, const int* in_sizes, int n_in,
                              void* d_out, int out_size, void* d_ws, size_t ws_size,
                              hipStream_t stream) {
    const float* x   = (const float*)d_in[0];
    const float* W1  = (const float*)d_in[1];
    const float* s1  = (const float*)d_in[2];
    const float* b1  = (const float*)d_in[3];
    const float* W2  = (const float*)d_in[4];
    const float* s2  = (const float*)d_in[5];
    const float* b2  = (const float*)d_in[6];
    const float* W3  = (const float*)d_in[7];
    const float* s3  = (const float*)d_in[8];
    const float* b3  = (const float*)d_in[9];
    const float* W4  = (const float*)d_in[10];
    const float* s4  = (const float*)d_in[11];
    const float* b4  = (const float*)d_in[12];
    const float* W5  = (const float*)d_in[13];
    const float* s5  = (const float*)d_in[14];
    const float* b5  = (const float*)d_in[15];
    const float* L1w = (const float*)d_in[16];
    const float* s6  = (const float*)d_in[17];
    const float* b6  = (const float*)d_in[18];
    const float* L2w = (const float*)d_in[19];
    const float* L2b = (const float*)d_in[20];
    const float* s7  = (const float*)d_in[21];
    const float* b7  = (const float*)d_in[22];
    const float* L3w = (const float*)d_in[23];
    const float* L3b = (const float*)d_in[24];
    const float* F1w = (const float*)d_in[25];
    const float* s8  = (const float*)d_in[26];
    const float* b8  = (const float*)d_in[27];
    const float* F2w = (const float*)d_in[28];
    const float* F2b = (const float*)d_in[29];
    const float* s9  = (const float*)d_in[30];
    const float* b9  = (const float*)d_in[31];
    const float* F3w = (const float*)d_in[32];
    const float* F3b = (const float*)d_in[33];

    float* ws = (float*)d_ws;
    size_t off = 0;
    auto alloc = [&](size_t n) { float* p = ws + off; off += n; return p; };
    float* pts  = alloc((size_t)Bn * Np * 4);
    float* x1   = alloc((size_t)Bn * Np * 64);
    float* x2   = alloc((size_t)Bn * Np * 64);
    float* x3   = alloc((size_t)Bn * Np * 128);
    float* x4   = alloc((size_t)Bn * Np * 256);
    float* xcm  = alloc((size_t)Bn * Np * 128);   // aliased: pmax / psum
    float* xxb  = alloc((size_t)Bn * Np);
    int*   idxb = (int*)alloc((size_t)Bn * Np * Kn);
    float* g0   = alloc((size_t)Bn * 2048);
    float* g1   = alloc((size_t)Bn * 512);
    float* g2   = alloc((size_t)Bn * 256);
    float* y1   = alloc((size_t)Bn * 512);
    float* y2   = alloc((size_t)Bn * 256);
    float* WnsT2 = alloc(64 * 64);
    float* WdsT2 = alloc(64 * 64);
    float* WnsT3 = alloc(64 * 128);
    float* WdsT3 = alloc(64 * 128);
    float* WnsT4 = alloc(128 * 256);
    float* WdsT4 = alloc(128 * 256);
    ushortT* Bh2 = (ushortT*)alloc(64 * 64 / 2);
    ushortT* Bl2 = (ushortT*)alloc(64 * 64 / 2);
    ushortT* Bh3 = (ushortT*)alloc(64 * 128 / 2);
    ushortT* Bl3 = (ushortT*)alloc(64 * 128 / 2);
    ushortT* Bh4 = (ushortT*)alloc(128 * 256 / 2);
    ushortT* Bl4 = (ushortT*)alloc(128 * 256 / 2);
    ushortT* BhK = (ushortT*)alloc(1048576);   // knn B-frag hi (max C=128: 2M shorts)
    ushortT* BlK = (ushortT*)alloc(1048576);
    ushortT* Bh5 = (ushortT*)alloc(262144);    // W5 frag hi: 512K shorts
    ushortT* Bl5 = (ushortT*)alloc(262144);
    float* pmax = xcm;
    float* psum = xcm + 524288;
    float* cb2 = x2;
    float* cb3 = x3;
    float* cb4 = x4;

    // dynamic-LDS opt-ins (idempotent, safe pre-capture)
    // dl is [16][514] f32 (4-pass column split)
    auto shsz = [](int CP) { return 16 * CP * 2 * 2 + 64 + 16 * 514 * 4; };
    int sh3 = shsz(40), sh64 = shsz(72), sh128 = shsz(136);
    int shw5 = 32 * 520 * 2 * 2;
    (void)hipFuncSetAttribute((const void*)k_knn5<3, 32, 4>, hipFuncAttributeMaxDynamicSharedMemorySize, sh3);
    (void)hipFuncSetAttribute((const void*)k_knn5<64, 64, 64>, hipFuncAttributeMaxDynamicSharedMemorySize, sh64);
    (void)hipFuncSetAttribute((const void*)k_knn5<128, 128, 128>, hipFuncAttributeMaxDynamicSharedMemorySize, sh128);
    (void)hipFuncSetAttribute((const void*)k_w5mfma, hipFuncAttributeMaxDynamicSharedMemorySize, shw5);

    k_transpose<<<Bn * Np / 256, 256, 0, stream>>>(x, pts);
    k_wsplit<<<16, 256, 0, stream>>>(W2, s2, 64, 64, WnsT2, WdsT2);
    k_wsplit<<<32, 256, 0, stream>>>(W3, s3, 64, 128, WnsT3, WdsT3);
    k_wsplit<<<128, 256, 0, stream>>>(W4, s4, 128, 256, WnsT4, WdsT4);
    k_wpack<<<2, 256, 0, stream>>>(W2, s2, 64, 64, Bh2, Bl2);
    k_wpack<<<4, 256, 0, stream>>>(W3, s3, 64, 128, Bh3, Bl3);
    k_wpack<<<16, 256, 0, stream>>>(W4, s4, 128, 256, Bh4, Bl4);
    k_w5pack<<<256, 256, 0, stream>>>(W5, s5, Bh5, Bl5);

    // Layer 1: C=3
    k_xx<<<Bn * Np / 4, 256, 0, stream>>>(pts, xxb, 3, 4);
    k_bpack<3, 32, 4><<<Bn * 1 * 32, 256, 0, stream>>>(pts, BhK, BlK);
    k_knn5<3, 32, 4><<<Bn * Np / 16, 1024, sh3, stream>>>(pts, BhK, BlK, xxb, idxb);
    k_edgeconv<3, 4, 64, 1, 8, 4><<<Bn * Np / 4, 256, 0, stream>>>(pts, idxb, W1, s1, b1, x1);

    // Layer 2: C=64 -> O=64
    k_xx<<<Bn * Np / 4, 256, 0, stream>>>(x1, xxb, 64, 64);
    k_bpack<64, 64, 64><<<Bn * 2 * 32, 256, 0, stream>>>(x1, BhK, BlK);
    k_knn5<64, 64, 64><<<Bn * Np / 16, 1024, sh64, stream>>>(x1, BhK, BlK, xxb, idxb);
    k_ctr<64, 64, 4><<<Bn * Np / 32, 256, 0, stream>>>(x1, WdsT2, b2, cb2);
    k_ec3<64, 64, 2><<<Bn * Np / 2, 256, 0, stream>>>(x1, idxb, Bh2, Bl2, cb2, x2);

    // Layer 3: C=64 -> O=128
    k_xx<<<Bn * Np / 4, 256, 0, stream>>>(x2, xxb, 64, 64);
    k_bpack<64, 64, 64><<<Bn * 2 * 32, 256, 0, stream>>>(x2, BhK, BlK);
    k_knn5<64, 64, 64><<<Bn * Np / 16, 1024, sh64, stream>>>(x2, BhK, BlK, xxb, idxb);
    k_ctr<64, 128, 8><<<Bn * Np / 32, 256, 0, stream>>>(x2, WdsT3, b3, cb3);
    k_ec3<64, 128, 2><<<Bn * Np / 2, 256, 0, stream>>>(x2, idxb, Bh3, Bl3, cb3, x3);

    // Layer 4: C=128 -> O=256
    k_xx<<<Bn * Np / 4, 256, 0, stream>>>(x3, xxb, 128, 128);
    k_bpack<128, 128, 128><<<Bn * 4 * 32, 256, 0, stream>>>(x3, BhK, BlK);
    k_knn5<128, 128, 128><<<Bn * Np / 16, 1024, sh128, stream>>>(x3, BhK, BlK, xxb, idxb);
    k_ctr<128, 256, 8><<<Bn * Np / 32, 256, 0, stream>>>(x3, WdsT4, b4, cb4);
    k_ec3<128, 256, 2><<<Bn * Np / 2, 256, 0, stream>>>(x3, idxb, Bh4, Bl4, cb4, x4);

    // W5 + pooling (MFMA, 16-wave blocks)
    k_w5mfma<<<Bn * 64, 1024, shw5, stream>>>(x1, x2, x3, x4, Bh5, Bl5, b5, pmax, psum);
    k_poolred<<<Bn * 1024 / 256, 256, 0, stream>>>(pmax, psum, g0);

    float* out = (float*)d_out;
    k_fc<<<dim3(128, Bn), 256, 0, stream>>>(g0, 2048, 2048, L1w, nullptr, s6, b6, 1, g1, 512, 512);
    k_fc<<<dim3(64, Bn), 256, 0, stream>>>(g1, 512, 512, L2w, L2b, s7, b7, 1, g2, 256, 256);
    k_fc<<<dim3(2, Bn), 256, 0, stream>>>(g2, 256, 256, L3w, L3b, nullptr, nullptr, 0, out, 5, 5);
    k_fc<<<dim3(128, Bn), 256, 0, stream>>>(g0, 2048, 1024, F1w, nullptr, s8, b8, 1, y1, 512, 512);
    k_fc<<<dim3(64, Bn), 256, 0, stream>>>(y1, 512, 512, F2w, F2b, s9, b9, 1, y2, 256, 256);
    k_fc<<<dim3(2, Bn), 256, 0, stream>>>(y2, 256, 256, F3w, F3b, nullptr, nullptr, 0, out + 40, 5, 5);
}